// Round 3
// baseline (136.102 us; speedup 1.0000x reference)
//
#include <hip/hip_runtime.h>
#include <hip/hip_bf16.h>

typedef __attribute__((ext_vector_type(8))) short bf16x8;
typedef __attribute__((ext_vector_type(4))) float f32x4;

// exp(v/T - 5) with T=0.2  ==  exp2( (v-1) * 5*log2(e) )
#define EXP_SCALE 7.213475204444817f

__device__ __forceinline__ float fast_exp2(float x) {
#if __has_builtin(__builtin_amdgcn_exp2f)
  return __builtin_amdgcn_exp2f(x);
#else
  return exp2f(x);
#endif
}

__device__ __forceinline__ unsigned short f32_to_bf16(float f) {
  unsigned int u = __float_as_uint(f);
  unsigned int r = (u + 0x7FFFu + ((u >> 16) & 1u)) >> 16;
  return (unsigned short)r;
}

// z is stored SWIZZLED in MFMA-fragment order:
//   shorts addr = tile*2048 + kk*512 + slot*8 + rem
// where tile = row>>4, c = row&15, element e of the row: kk = e>>5,
// q = (e>>3)&3, rem = e&7, slot = q*16 + c.
// Then a wave (lane = q*16+c) loads one (tile,kk) fragment as a fully
// contiguous 1KB global_load_dwordx4 at z + tile*2048 + kk*512 + lane*8.

// Kernel 1: L2-normalize rows -> swizzled bf16 z. Also zeroes out[0]
// (stream-ordered before k_finish's atomicAdd).
__global__ __launch_bounds__(256) void k_normalize(
    const float* __restrict__ emb_i, const float* __restrict__ emb_j,
    unsigned short* __restrict__ z, float* __restrict__ out)
{
  if (blockIdx.x == 0 && threadIdx.x == 0) out[0] = 0.0f;
  const int w = threadIdx.x >> 6;
  const int lane = threadIdx.x & 63;
  const int row = (blockIdx.x << 2) + w;
  const float* src = (row < 4096) ? (emb_i + row * 128) : (emb_j + (row - 4096) * 128);
  float2 v = reinterpret_cast<const float2*>(src)[lane];
  float ss = v.x * v.x + v.y * v.y;
  #pragma unroll
  for (int m = 1; m < 64; m <<= 1) ss += __shfl_xor(ss, m, 64);
  float rinv = 1.0f / sqrtf(ss);
  ushort2 st;
  st.x = f32_to_bf16(v.x * rinv);
  st.y = f32_to_bf16(v.y * rinv);
  // element e = 2*lane of this row -> swizzled address
  const int e = lane << 1;
  const int kk = e >> 5;
  const int q = (e >> 3) & 3;
  const int rem = e & 7;
  const int tile = row >> 4;
  const int c = row & 15;
  unsigned short* dst = z + tile * 2048 + kk * 512 + ((q << 4) + c) * 8 + rem;
  *reinterpret_cast<ushort2*>(dst) = st;
}

// Kernel 2: block = 64 rows x 1024-col chunk; 4 waves each own all 64 rows
// (A in regs, 16 bf16x8) and walk 16 col-tiles (16 cols each, stride 4 tiles).
// Fully unrolled, 3-slot register pipeline, prefetch distance 2.
// Diagonal exp term (==1) is NOT excluded here; k_finish subtracts 1.
__global__ __launch_bounds__(256, 3) void k_simlse(
    const unsigned short* __restrict__ z,
    float* __restrict__ rowsum,   // [8][8192]
    float* __restrict__ rowpos)   // [8192]
{
  const int w = threadIdx.x >> 6;
  const int lane = threadIdx.x & 63;
  const int q = lane >> 4;
  const int c = lane & 15;
  const int rb = blockIdx.x >> 3;       // 0..127
  const int ch = blockIdx.x & 7;        // 0..7
  const int R0 = rb << 6;               // 64-row block

  // A fragments: tiles R0/16 .. R0/16+3, each kk 0..3; contiguous 1KB loads
  bf16x8 a[4][4];
  {
    const unsigned short* ap = z + (R0 >> 4) * 2048 + (lane << 3);
    #pragma unroll
    for (int rg = 0; rg < 4; ++rg)
      #pragma unroll
      for (int kk = 0; kk < 4; ++kk)
        a[rg][kk] = *reinterpret_cast<const bf16x8*>(ap + rg * 2048 + kk * 512);
  }

  float acc[4][4];
  #pragma unroll
  for (int rg = 0; rg < 4; ++rg)
    #pragma unroll
    for (int e = 0; e < 4; ++e) acc[rg][e] = 0.0f;
  float pacc[4] = {0.f, 0.f, 0.f, 0.f};

  const int ct0 = (ch << 6) + w;                  // first 16-col tile
  const int pos0 = ((R0 + 4096) & 8191) >> 4;     // pos tile for rg is pos0+rg
  // wave w's pos tile is pos0+w (pos0 % 4 == 0); present iff in this chunk
  const int i_pos = ((pos0 >> 6) == ch) ? ((pos0 - (ch << 6)) >> 2) : -1;

  const unsigned short* bwave = z + ct0 * 2048 + (lane << 3);

  bf16x8 b[3][4];
  #pragma unroll
  for (int kk = 0; kk < 4; ++kk) {
    b[0][kk] = *reinterpret_cast<const bf16x8*>(bwave + kk * 512);
    b[1][kk] = *reinterpret_cast<const bf16x8*>(bwave + 8192 + kk * 512);
  }

  #pragma unroll
  for (int i = 0; i < 16; ++i) {
    if (i < 14) {
      const unsigned short* p = bwave + (i + 2) * 8192;
      #pragma unroll
      for (int kk = 0; kk < 4; ++kk)
        b[(i + 2) % 3][kk] = *reinterpret_cast<const bf16x8*>(p + kk * 512);
    }
    f32x4 cc[4];
    #pragma unroll
    for (int rg = 0; rg < 4; ++rg) cc[rg] = f32x4{0.f, 0.f, 0.f, 0.f};
    #pragma unroll
    for (int kk = 0; kk < 4; ++kk)
      #pragma unroll
      for (int rg = 0; rg < 4; ++rg)
        cc[rg] = __builtin_amdgcn_mfma_f32_16x16x32_bf16(a[rg][kk], b[i % 3][kk], cc[rg], 0, 0, 0);
    #pragma unroll
    for (int rg = 0; rg < 4; ++rg)
      #pragma unroll
      for (int e = 0; e < 4; ++e)
        acc[rg][e] += fast_exp2(EXP_SCALE * (cc[rg][e] - 1.0f));
    if (i == i_pos) {   // rare, wave-uniform scalar compare
      #pragma unroll
      for (int rg = 0; rg < 4; ++rg) {
        if (w == rg) {
          #pragma unroll
          for (int e = 0; e < 4; ++e)
            if (c == ((q << 2) + e)) pacc[e] = cc[rg][e] * 5.0f;
        }
      }
    }
  }

  // Reduce over the 16 cols (c-group: xor masks 1,2,4,8)
  #pragma unroll
  for (int m = 1; m < 16; m <<= 1) {
    #pragma unroll
    for (int rg = 0; rg < 4; ++rg)
      #pragma unroll
      for (int e = 0; e < 4; ++e)
        acc[rg][e] += __shfl_xor(acc[rg][e], m, 64);
    #pragma unroll
    for (int e = 0; e < 4; ++e) pacc[e] += __shfl_xor(pacc[e], m, 64);
  }

  __shared__ float lsum[4][64];
  __shared__ float lpos[4][16];
  if (c == 0) {
    #pragma unroll
    for (int rg = 0; rg < 4; ++rg)
      #pragma unroll
      for (int e = 0; e < 4; ++e)
        lsum[w][(rg << 4) + (q << 2) + e] = acc[rg][e];
    #pragma unroll
    for (int e = 0; e < 4; ++e) lpos[w][(q << 2) + e] = pacc[e];
  }
  __syncthreads();
  if (threadIdx.x < 64) {
    const int t = threadIdx.x;
    const int r = R0 + t;
    float s = lsum[0][t] + lsum[1][t] + lsum[2][t] + lsum[3][t];
    rowsum[(ch << 13) + r] = s;
    const int P = (R0 + 4096) & 8191;
    if (ch == (P >> 10))                 // this chunk owns the positive cols
      rowpos[r] = lpos[t >> 4][t & 15];
  }
}

// Kernel 3: tot = sum over 8 chunks minus the diagonal term (==1 for
// unit-norm rows); lse = 5 + log(tot); loss = mean(lse - pos).
__global__ __launch_bounds__(256) void k_finish(
    const float* __restrict__ rowsum, const float* __restrict__ rowpos,
    float* __restrict__ out)
{
  const int r = blockIdx.x * 256 + threadIdx.x;
  float tot = -1.0f;
  #pragma unroll
  for (int chunk = 0; chunk < 8; ++chunk) tot += rowsum[(chunk << 13) + r];
  float v = 5.0f + logf(tot) - rowpos[r];
  #pragma unroll
  for (int m = 1; m < 64; m <<= 1) v += __shfl_xor(v, m, 64);
  __shared__ float red[4];
  if ((threadIdx.x & 63) == 0) red[threadIdx.x >> 6] = v;
  __syncthreads();
  if (threadIdx.x == 0)
    atomicAdd(out, (red[0] + red[1] + red[2] + red[3]) * (1.0f / 8192.0f));
}

extern "C" void kernel_launch(void* const* d_in, const int* in_sizes, int n_in,
                              void* d_out, int out_size, void* d_ws, size_t ws_size,
                              hipStream_t stream) {
  const float* emb_i = (const float*)d_in[0];
  const float* emb_j = (const float*)d_in[1];
  unsigned short* z = (unsigned short*)d_ws;                       // 8192*128*2 = 2 MB (swizzled)
  float* rowsum = (float*)((char*)d_ws + 8192 * 128 * 2);          // [8][8192] = 256 KB
  float* rowpos = rowsum + 8 * 8192;                               // [8192] = 32 KB
  float* out = (float*)d_out;

  k_normalize<<<2048, 256, 0, stream>>>(emb_i, emb_j, z, out);
  k_simlse<<<1024, 256, 0, stream>>>(z, rowsum, rowpos);
  k_finish<<<32, 256, 0, stream>>>(rowsum, rowpos, out);
}